// Round 5
// baseline (309.131 us; speedup 1.0000x reference)
//
#include <hip/hip_runtime.h>
#include <string.h>

// TSK fuzzy model forward.  N=32768 rows, D=64 dims, R=32 rules.
// Inputs fp32 (proven R3: 8 MB Xz read, no fault).  Output fp32 (proven R4:
// bf16-packed writes produced the exact "scrambled y" error signature 41.875
// vs ref-max 33.75; threshold = 2% of ref-max, not bf16-eps).
// Outputs concatenated flat: y[N], w[N*R], Phi[N*R*(D+1)]  (fp32).
// Memory-bound on the Phi write (~273 MB fp32) -> coalesced float4 streaming.

constexpr int N_ROWS = 32768;
constexpr int D = 64;
constexpr int R = 32;
constexpr float EPS = 1e-12f;
constexpr int ROWS_PER_BLOCK = 8;
constexpr int BLOCK = 256;
constexpr int PHI_COLS = R * (D + 1);  // 2080

__global__ __launch_bounds__(BLOCK) void tsk_kernel(
    const float* __restrict__ Xz,
    const float* __restrict__ centers,
    const float* __restrict__ sigmas,
    const float* __restrict__ theta,
    float* __restrict__ y_out,
    float* __restrict__ w_out,
    float* __restrict__ phi_out)
{
    // stride 65 -> bank (r+d)%32: conflict-free when 32 lanes sweep r at fixed d
    __shared__ float c_lds[R][D + 1];
    __shared__ float is_lds[R][D + 1];
    __shared__ float th_lds[R][D + 1];
    __shared__ float x_lds[ROWS_PER_BLOCK][D + 1];
    __shared__ float w_lds[ROWS_PER_BLOCK][R + 1];

    const int tid = threadIdx.x;
    const int row0 = blockIdx.x * ROWS_PER_BLOCK;

    // ---- stage constants into LDS (inv-sigma precomputed) ----
    for (int i = tid; i < R * D; i += BLOCK) {
        int r = i >> 6, d = i & 63;
        c_lds[r][d] = centers[i];
        is_lds[r][d] = 1.0f / (sigmas[i] + EPS);
    }
    for (int i = tid; i < R * (D + 1); i += BLOCK)
        th_lds[i / 65][i % 65] = theta[i];

    // ---- stage this block's 8 rows of x: 512 floats = 128 float4 ----
    if (tid < 128) {
        const float4* x4 = (const float4*)(Xz + (size_t)row0 * D);
        float4 v = x4[tid];
        int e = 4 * tid;                 // 0..508
        int rr = e >> 6, cc = e & 63;
        x_lds[rr][cc]     = v.x;
        x_lds[rr][cc + 1] = v.y;
        x_lds[rr][cc + 2] = v.z;
        x_lds[rr][cc + 3] = v.w;
    }
    __syncthreads();

    // ---- phase 1: thread = (local_row, rule) ----
    const int lrow = tid >> 5;   // 0..7
    const int r = tid & 31;      // 0..31
    float acc = 0.0f;
    float tdot = th_lds[r][0];
#pragma unroll
    for (int d = 0; d < D; ++d) {
        float x = x_lds[lrow][d];
        float z = (x - c_lds[r][d]) * is_lds[r][d];
        acc = fmaf(z, z, acc);
        tdot = fmaf(th_lds[r][d + 1], x, tdot);
    }
    float logw = -0.5f * acc;

    // softmax over the 32 rule-lanes of this row
    float m = logw;
#pragma unroll
    for (int off = 16; off >= 1; off >>= 1)
        m = fmaxf(m, __shfl_xor(m, off, 32));
    float ex = __expf(logw - m);
    float s = ex;
#pragma unroll
    for (int off = 16; off >= 1; off >>= 1)
        s += __shfl_xor(s, off, 32);
    float w = ex / (s + EPS);
    w_lds[lrow][r] = w;
    w_out[(size_t)(row0 + lrow) * R + r] = w;

    // y = sum_r w_r * (theta_r . [1,x])
    float yc = w * tdot;
#pragma unroll
    for (int off = 16; off >= 1; off >>= 1)
        yc += __shfl_xor(yc, off, 32);
    if (r == 0) y_out[row0 + lrow] = yc;
    __syncthreads();

    // ---- phase 2: stream Phi as float4 (16 B/lane), fully coalesced ----
    // phi_out base byte offset 4,325,376 and row stride 8320 B are both
    // 16B-aligned; 2080 floats/row = 520 float4, last store ends at buffer end.
    for (int k = tid; k < PHI_COLS / 4; k += BLOCK) {
        int e = 4 * k;
        int r0 = (e + 0) / 65, j0 = (e + 0) - r0 * 65;
        int r1 = (e + 1) / 65, j1 = (e + 1) - r1 * 65;
        int r2 = (e + 2) / 65, j2 = (e + 2) - r2 * 65;
        int r3 = (e + 3) / 65, j3 = (e + 3) - r3 * 65;
#pragma unroll
        for (int row = 0; row < ROWS_PER_BLOCK; ++row) {
            float4 o;
            o.x = w_lds[row][r0] * ((j0 == 0) ? 1.0f : x_lds[row][j0 - 1]);
            o.y = w_lds[row][r1] * ((j1 == 0) ? 1.0f : x_lds[row][j1 - 1]);
            o.z = w_lds[row][r2] * ((j2 == 0) ? 1.0f : x_lds[row][j2 - 1]);
            o.w = w_lds[row][r3] * ((j3 == 0) ? 1.0f : x_lds[row][j3 - 1]);
            ((float4*)(phi_out + (size_t)(row0 + row) * PHI_COLS))[k] = o;
        }
    }
}

extern "C" void kernel_launch(void* const* d_in, const int* in_sizes, int n_in,
                              void* d_out, int out_size, void* d_ws, size_t ws_size,
                              hipStream_t stream) {
    const float* Xz      = (const float*)d_in[0];
    const float* centers = (const float*)d_in[1];
    const float* sigmas  = (const float*)d_in[2];
    const float* theta   = (const float*)d_in[3];

    float* out = (float*)d_out;
    float* y_out   = out;
    float* w_out   = out + N_ROWS;
    float* phi_out = out + N_ROWS + (size_t)N_ROWS * R;

    dim3 grid(N_ROWS / ROWS_PER_BLOCK);
    tsk_kernel<<<grid, BLOCK, 0, stream>>>(Xz, centers, sigmas, theta,
                                           y_out, w_out, phi_out);
}